// Round 10
// baseline (405.390 us; speedup 1.0000x reference)
//
#include <hip/hip_runtime.h>
#include <math.h>

// Problem constants
#define Tn 30
#define Bn 16384
#define Hn 100
#define Pn 7

// Tiling: gates padded 100->128 units => N=512 (32 n-tiles); K padded 100->128 (4 kt of 32).
// 512 blocks x 512 threads (8 waves), 32 batch rows per block (2 row-groups) ->
// 2 blocks/CU, 16 waves/CU, 4 waves/SIMD (R9 had 2/SIMD; VALU latency was exposed).
// __launch_bounds__(512,4) pins VGPR cap 128 (R9 compiled to exactly 128 with MORE state).
// Wave ag owns unit-block ag (16 units, all 4 gates) for both row-groups.
// B-frags (16/wave = 64 VGPR) in registers. gin2 in 8 packed-bf16 uint2 VGPRs.
// h double-buffered in LDS, frag-major [rg][kt][cell][8] with XOR swizzle
// cell = s*16 + (m^s): reads conflict-free ds_read_b128, b16 writes 2-way same-dword
// (free, m136; R9 measured 0 conflicts). 1 barrier/step.
#define NFRAG 128                      // B-frags per matrix (32 nt x 4 kt)
#define FRAG_BYTES (NFRAG * 64 * 16)   // 131072 per matrix
#define WS_FRAG_OFF 4096
#define WS_W2_OFF (WS_FRAG_OFF + 3 * FRAG_BYTES)   // 28 W2 frags (7 ps x 4 kt)
#define HBF_USH 4096                   // one h buffer: 2 rg x 4 kt x 64 cells x 8 ush (8 KB)

typedef __attribute__((ext_vector_type(8))) short short8;   // 8 bf16 (4 VGPRs)
typedef __attribute__((ext_vector_type(4))) float floatx4;  // MFMA C/D

__device__ __forceinline__ float rcp_(float v) { return __builtin_amdgcn_rcpf(v); }
__device__ __forceinline__ float sig_(float v) { return rcp_(1.0f + __expf(-v)); }
__device__ __forceinline__ float tanh_(float v) { return 1.0f - 2.0f * rcp_(__expf(2.0f * v) + 1.0f); }
__device__ __forceinline__ unsigned f2bf(float v) {
    unsigned u = __float_as_uint(v);
    return (u + 0x7FFFu + ((u >> 16) & 1u)) >> 16;   // RNE
}

// A-frag read, XOR-swizzled frag-major layout: cell(m,s) = s*16 + (m^s).
// Lane (l,q) needs A[m=l][k=kt*32+q*8+j] -> cell q*16 + (l^q).
__device__ __forceinline__ short8 ld_af(const unsigned short* buf, int rg, int kt, int l, int q) {
    return *(const short8*)(buf + ((rg * 4 + kt) * 64 + q * 16 + (l ^ q)) * 8);
}

// Merged prep: gid<512 -> u1/wc1 rank-1 FC1 fold; else pack Whh1/Wih2/Whh2 + W2 B-frags.
// B[k][n]: n = lane&15, k = (lane>>4)*8 + jj  (16x16x32 bf16 B mapping, HW-verified R4-R9).
__global__ void prep_kernel(const float* __restrict__ W1, const float* __restrict__ b1,
                            const float* __restrict__ Wih1, const float* __restrict__ bih1,
                            const float* __restrict__ bhh1, const float* __restrict__ Whh1,
                            const float* __restrict__ Wih2, const float* __restrict__ Whh2,
                            const float* __restrict__ W2, float* __restrict__ ws) {
    int gid = blockIdx.x * 256 + threadIdx.x;   // 512 + 3*8192 + 1792 = 26880 total
    if (gid < 512) {
        int j = gid;
        if (j < 400) {
            float u = 0.f, w = 0.f;
            for (int k = 0; k < Hn; ++k) {
                float a = Wih1[j * Hn + k];
                u += a * W1[k];
                w += a * b1[k];
            }
            ws[j] = u;
            ws[400 + j] = w + bih1[j] + bhh1[j];
        }
        return;
    }
    int g = gid - 512;
    int lane = g & 63;
    int l = lane & 15, q = lane >> 4;
    unsigned short hh[8];
    uint4 u;
    if (g < 3 * NFRAG * 64) {
        int mat = g / (NFRAG * 64);
        int f = (g % (NFRAG * 64)) >> 6;
        int nt = f >> 2, kt = f & 3;
        int G = nt >> 3, ag = nt & 7;
        int j = ag * 16 + l;
        const float* W = (mat == 0) ? Whh1 : (mat == 1) ? Wih2 : Whh2;
        const float* wrow = W + (G * Hn + (j < Hn ? j : 0)) * Hn;
        int kbase = kt * 32 + q * 8;
#pragma unroll
        for (int jj = 0; jj < 8; ++jj) {
            int k = kbase + jj;
            hh[jj] = (j < Hn && k < Hn) ? (unsigned short)f2bf(wrow[k]) : (unsigned short)0;
        }
        u.x = (unsigned)hh[0] | ((unsigned)hh[1] << 16);
        u.y = (unsigned)hh[2] | ((unsigned)hh[3] << 16);
        u.z = (unsigned)hh[4] | ((unsigned)hh[5] << 16);
        u.w = (unsigned)hh[6] | ((unsigned)hh[7] << 16);
        ((uint4*)((char*)ws + WS_FRAG_OFF + mat * FRAG_BYTES))[f * 64 + lane] = u;
    } else {
        int t = g - 3 * NFRAG * 64;             // 0..1791
        int f = t >> 6;                         // ps*4 + kt
        int ps = f >> 2, kt = f & 3;
        int kbase = kt * 32 + q * 8;
#pragma unroll
        for (int jj = 0; jj < 8; ++jj) {
            int k = kbase + jj;
            hh[jj] = (l < Pn && k < Hn) ? (unsigned short)f2bf(W2[l * (Pn * Hn) + ps * Hn + k])
                                        : (unsigned short)0;
        }
        u.x = (unsigned)hh[0] | ((unsigned)hh[1] << 16);
        u.y = (unsigned)hh[2] | ((unsigned)hh[3] << 16);
        u.z = (unsigned)hh[4] | ((unsigned)hh[5] << 16);
        u.w = (unsigned)hh[6] | ((unsigned)hh[7] << 16);
        ((uint4*)((char*)ws + WS_W2_OFF))[f * 64 + lane] = u;
    }
}

__global__ __launch_bounds__(512, 4) void lstm_fused(
    const float* __restrict__ x,     // (T,B)
    const float* __restrict__ ws,    // u1/wc1 + packed frags
    const float* __restrict__ bih2,
    const float* __restrict__ bhh2,
    const float* __restrict__ b2,    // (7,)
    float* __restrict__ out)         // (B,7)
{
    __shared__ unsigned short sm[2 * HBF_USH];  // 16 KB: h double buffer, frag-major swizzled
    unsigned short* hb0 = sm;
    unsigned short* hb1 = sm + HBF_USH;

    const int tid = threadIdx.x;
    const int ag = tid >> 6, lane = tid & 63;   // wave id == unit-block id
    const int l = lane & 15, q = lane >> 4;
    const int jcol = ag * 16 + l;               // unit column (0..127; <100 real)
    const int rowbase = blockIdx.x * 32;

    // h-write constants for this lane's unit jcol (k-dim position jcol):
    // s_w = (jcol>>3)&3; ush addr = rg*2048 + hwconst + ((4q+r)^s_w)*8
    const int s_w = ((ag & 1) << 1) | (l >> 3);
    const int hwconst = (((ag >> 1) * 64 + s_w * 16) << 3) + (l & 7);

    // zero both h buffers (covers K-pad; pad units stay exactly 0 through the recurrence)
    for (int i = tid; i < HBF_USH; i += 512) ((unsigned*)sm)[i] = 0;

    // this wave's 16 Whh1 B-frags -> registers (64 VGPR, held for all 30 steps)
    short8 bf[4][4];   // [G][kt]
    const short8* fr0 = (const short8*)((const char*)ws + WS_FRAG_OFF);
#pragma unroll
    for (int G = 0; G < 4; ++G)
#pragma unroll
        for (int kt = 0; kt < 4; ++kt)
            bf[G][kt] = fr0[((((G << 3) | ag) << 2) + kt) * 64 + lane];

    float u1v[4], wc1v[4];
#pragma unroll
    for (int G = 0; G < 4; ++G) {
        u1v[G] = (jcol < Hn) ? ws[G * Hn + jcol] : 0.f;
        wc1v[G] = (jcol < Hn) ? ws[400 + G * Hn + jcol] : 0.f;
    }
    floatx4 cst[2];   // cell state per rg, rows 4q+r, unit jcol
    cst[0] = (floatx4){0.f, 0.f, 0.f, 0.f};
    cst[1] = (floatx4){0.f, 0.f, 0.f, 0.f};

    __syncthreads();   // h buffers zeroed

    // ---- Phase 1: LSTM1, 30 steps, 1 barrier/step ----
    for (int t = 0; t < Tn; ++t) {
        const unsigned short* hc = (t & 1) ? hb1 : hb0;
        unsigned short* hn = (t & 1) ? hb0 : hb1;
#pragma unroll
        for (int rg = 0; rg < 2; ++rg) {
            float4 xv = *(const float4*)(x + t * Bn + rowbase + rg * 16 + 4 * q);
            floatx4 acc[4];
#pragma unroll
            for (int G = 0; G < 4; ++G)
#pragma unroll
                for (int r = 0; r < 4; ++r)
                    acc[G][r] = fmaf(xv[r], u1v[G], wc1v[G]);
#pragma unroll
            for (int kt = 0; kt < 4; ++kt) {
                short8 a = ld_af(hc, rg, kt, l, q);
#pragma unroll
                for (int G = 0; G < 4; ++G)
                    acc[G] = __builtin_amdgcn_mfma_f32_16x16x32_bf16(a, bf[G][kt], acc[G], 0, 0, 0);
            }
#pragma unroll
            for (int r = 0; r < 4; ++r) {
                float iv = sig_(acc[0][r]);
                float fv = sig_(acc[1][r]);
                float gv = tanh_(acc[2][r]);
                float ov = sig_(acc[3][r]);
                float cc = fv * cst[rg][r] + iv * gv;
                cst[rg][r] = cc;
                hn[rg * 2048 + hwconst + (((4 * q + r) ^ s_w) << 3)] =
                    (unsigned short)f2bf(ov * tanh_(cc));
            }
        }
        __syncthreads();
    }
    // hb0 holds `last` (h after t=29).

    // ---- Wih2 frags; gin2 = bias2 + last·Wih2^T kept in 8 packed-bf16 uint2 VGPRs ----
    {
        const short8* fr = (const short8*)((const char*)ws + WS_FRAG_OFF + FRAG_BYTES);
#pragma unroll
        for (int G = 0; G < 4; ++G)
#pragma unroll
            for (int kt = 0; kt < 4; ++kt)
                bf[G][kt] = fr[((((G << 3) | ag) << 2) + kt) * 64 + lane];
    }
    uint2 g2r[2][4];   // [rg][G] packed bf16 gin2 (wave-private cells)
    {
        float bv[4];
#pragma unroll
        for (int G = 0; G < 4; ++G)
            bv[G] = (jcol < Hn) ? (bih2[G * Hn + jcol] + bhh2[G * Hn + jcol]) : 0.f;
#pragma unroll
        for (int rg = 0; rg < 2; ++rg) {
            floatx4 acc[4];
#pragma unroll
            for (int G = 0; G < 4; ++G)
                acc[G] = (floatx4){bv[G], bv[G], bv[G], bv[G]};
#pragma unroll
            for (int kt = 0; kt < 4; ++kt) {
                short8 a = ld_af(hb0, rg, kt, l, q);
#pragma unroll
                for (int G = 0; G < 4; ++G)
                    acc[G] = __builtin_amdgcn_mfma_f32_16x16x32_bf16(a, bf[G][kt], acc[G], 0, 0, 0);
            }
#pragma unroll
            for (int G = 0; G < 4; ++G) {
                g2r[rg][G].x = f2bf(acc[G][0]) | (f2bf(acc[G][1]) << 16);
                g2r[rg][G].y = f2bf(acc[G][2]) | (f2bf(acc[G][3]) << 16);
            }
        }
    }
    // ---- Whh2 frags ----
    {
        const short8* fr = (const short8*)((const char*)ws + WS_FRAG_OFF + 2 * FRAG_BYTES);
#pragma unroll
        for (int G = 0; G < 4; ++G)
#pragma unroll
            for (int kt = 0; kt < 4; ++kt)
                bf[G][kt] = fr[((((G << 3) | ag) << 2) + kt) * 64 + lane];
    }

    // ---- Phase 2: LSTM2, 7 steps; FC2 via MFMA on waves ag<2 (rg = ag) ----
    const short8* w2fr = (const short8*)((const char*)ws + WS_W2_OFF);
    floatx4 yfc = (floatx4){0.f, 0.f, 0.f, 0.f};

    for (int ps = 0; ps < Pn; ++ps) {
        int t = Tn + ps;
        const unsigned short* hc = (t & 1) ? hb1 : hb0;
        unsigned short* hn = (t & 1) ? hb0 : hb1;
#pragma unroll
        for (int rg = 0; rg < 2; ++rg) {
            floatx4 acc[4];
#pragma unroll
            for (int G = 0; G < 4; ++G) {
                acc[G][0] = __uint_as_float(g2r[rg][G].x << 16);
                acc[G][1] = __uint_as_float(g2r[rg][G].x & 0xFFFF0000u);
                acc[G][2] = __uint_as_float(g2r[rg][G].y << 16);
                acc[G][3] = __uint_as_float(g2r[rg][G].y & 0xFFFF0000u);
            }
#pragma unroll
            for (int kt = 0; kt < 4; ++kt) {
                short8 a = ld_af(hc, rg, kt, l, q);
#pragma unroll
                for (int G = 0; G < 4; ++G)
                    acc[G] = __builtin_amdgcn_mfma_f32_16x16x32_bf16(a, bf[G][kt], acc[G], 0, 0, 0);
            }
#pragma unroll
            for (int r = 0; r < 4; ++r) {
                float iv = sig_(acc[0][r]);
                float fv = sig_(acc[1][r]);
                float gv = tanh_(acc[2][r]);
                float ov = sig_(acc[3][r]);
                float cc = fv * cst[rg][r] + iv * gv;
                cst[rg][r] = cc;
                hn[rg * 2048 + hwconst + (((4 * q + r) ^ s_w) << 3)] =
                    (unsigned short)f2bf(ov * tanh_(cc));
            }
        }
        // FC2: y[row][p] += h2^(ps) · W2-slice(ps-1); hc = h2 of previous step (stable)
        if (ag < 2 && ps >= 1) {
#pragma unroll
            for (int kt = 0; kt < 4; ++kt) {
                short8 a = ld_af(hc, ag, kt, l, q);
                short8 wf = w2fr[((ps - 1) * 4 + kt) * 64 + lane];
                yfc = __builtin_amdgcn_mfma_f32_16x16x32_bf16(a, wf, yfc, 0, 0, 0);
            }
        }
        __syncthreads();
    }

    // ---- final FC2 (h2^(7) in hb1: t=36 even -> hn=hb1, slice 6), bias+sigmoid+store ----
    if (ag < 2) {
#pragma unroll
        for (int kt = 0; kt < 4; ++kt) {
            short8 a = ld_af(hb1, ag, kt, l, q);
            short8 wf = w2fr[(6 * 4 + kt) * 64 + lane];
            yfc = __builtin_amdgcn_mfma_f32_16x16x32_bf16(a, wf, yfc, 0, 0, 0);
        }
        if (l < Pn) {
            float bias = b2[l];
#pragma unroll
            for (int r = 0; r < 4; ++r)
                out[(rowbase + ag * 16 + 4 * q + r) * Pn + l] = sig_(yfc[r] + bias);
        }
    }
}

extern "C" void kernel_launch(void* const* d_in, const int* in_sizes, int n_in,
                              void* d_out, int out_size, void* d_ws, size_t ws_size,
                              hipStream_t stream) {
    const float* x    = (const float*)d_in[0];
    const float* W1   = (const float*)d_in[1];
    const float* b1   = (const float*)d_in[2];
    const float* Wih1 = (const float*)d_in[3];
    const float* Whh1 = (const float*)d_in[4];
    const float* bih1 = (const float*)d_in[5];
    const float* bhh1 = (const float*)d_in[6];
    const float* Wih2 = (const float*)d_in[7];
    const float* Whh2 = (const float*)d_in[8];
    const float* bih2 = (const float*)d_in[9];
    const float* bhh2 = (const float*)d_in[10];
    const float* W2   = (const float*)d_in[11];
    const float* b2   = (const float*)d_in[12];
    float* out = (float*)d_out;
    float* ws  = (float*)d_ws;

    prep_kernel<<<(512 + 3 * NFRAG * 64 + 28 * 64) / 256, 256, 0, stream>>>(
        W1, b1, Wih1, bih1, bhh1, Whh1, Wih2, Whh2, W2, ws);
    lstm_fused<<<Bn / 32, 512, 0, stream>>>(x, ws, bih2, bhh2, b2, out);
}

// Round 11
// 236.219 us; speedup vs baseline: 1.7162x; 1.7162x over previous
//
#include <hip/hip_runtime.h>
#include <math.h>

// Problem constants
#define Tn 30
#define Bn 16384
#define Hn 100
#define Pn 7

// R9 structure (best: 168us kernel), prep FUSED into the single kernel:
// every block converts its own weight fragments from raw f32 (deterministic, ~2us),
// eliminating the prep dispatch + inter-dispatch gap (~55us of wall).
// 256 blocks x 512 threads (8 waves). Wave ag owns unit-block ag (16 units, all 4
// gates) for ALL 4 row-groups. Gates padded 100->128 => N=512; K padded 100->128.
// B-frags (16/wave = 64 VGPR) in registers; gin2 in packed-bf16 VGPRs.
// h double-buffered in LDS, frag-major [rg][kt][cell][8], XOR swizzle cell=s*16+(m^s):
// conflict-free ds_read_b128 + free 2-way b16 writes (R9 measured 0 conflicts).
// __launch_bounds__(512,2): 128 arch VGPRs, no spill (4 waves/SIMD proven impossible
// for this live set -- R7/R8/R10 all spilled 300+ GB).
#define HBF_USH 8192                   // one h buffer: 4 rg x 4 kt x 64 cells x 8 ush (16 KB)

typedef __attribute__((ext_vector_type(8))) short short8;   // 8 bf16 (4 VGPRs)
typedef __attribute__((ext_vector_type(4))) float floatx4;  // MFMA C/D

__device__ __forceinline__ float rcp_(float v) { return __builtin_amdgcn_rcpf(v); }
__device__ __forceinline__ float sig_(float v) { return rcp_(1.0f + __expf(-v)); }
__device__ __forceinline__ float tanh_(float v) { return 1.0f - 2.0f * rcp_(__expf(2.0f * v) + 1.0f); }
__device__ __forceinline__ unsigned f2bf(float v) {
    unsigned u = __float_as_uint(v);
    return (u + 0x7FFFu + ((u >> 16) & 1u)) >> 16;   // RNE
}

__device__ __forceinline__ short8 pack_bf8(const float v[8]) {
    union { short8 s; uint4 u; } r;
    r.u.x = f2bf(v[0]) | (f2bf(v[1]) << 16);
    r.u.y = f2bf(v[2]) | (f2bf(v[3]) << 16);
    r.u.z = f2bf(v[4]) | (f2bf(v[5]) << 16);
    r.u.w = f2bf(v[6]) | (f2bf(v[7]) << 16);
    return r.s;
}

// Build this wave's 16 B-frags for one gate matrix (400x100 f32, gate-major) directly
// from global. B[k][n]: n = lane&15 (unit jc), k = (lane>>4)*8 + jj (HW-verified R4-R9).
// Pad: jc>=100 or k>=100 -> 0.
__device__ __forceinline__ void load_gate_bfrags(const float* __restrict__ W, int jc, int q,
                                                 short8 bf[4][4]) {
    const bool jok = (jc < Hn);
    const int row = jok ? jc : 0;
#pragma unroll
    for (int G = 0; G < 4; ++G) {
        const float* wrow = W + (G * Hn + row) * Hn;
#pragma unroll
        for (int kt = 0; kt < 4; ++kt) {
            int kb = kt * 32 + q * 8;   // multiple of 8
            float v[8];
#pragma unroll
            for (int jj = 0; jj < 8; ++jj) v[jj] = 0.f;
            if (jok && kb < Hn) {       // kb <= 96; first 4 (kb..kb+3) always valid
                float4 a = *(const float4*)(wrow + kb);
                v[0] = a.x; v[1] = a.y; v[2] = a.z; v[3] = a.w;
                if (kb + 4 < Hn) {      // kb <= 88: second 4 valid too
                    float4 b = *(const float4*)(wrow + kb + 4);
                    v[4] = b.x; v[5] = b.y; v[6] = b.z; v[7] = b.w;
                }
            }
            bf[G][kt] = pack_bf8(v);
        }
    }
}

// One W2 B-frag for FC2 slice s (W2 is (7,700)): n-col = p (7 of 16 lanes real).
__device__ __forceinline__ short8 load_w2_frag(const float* __restrict__ W2, int s, int kt,
                                               int l, int q) {
    int kb = kt * 32 + q * 8;
    float v[8];
#pragma unroll
    for (int jj = 0; jj < 8; ++jj) v[jj] = 0.f;
    if (l < Pn && kb < Hn) {
        const float* wrow = W2 + l * (Pn * Hn) + s * Hn;
        float4 a = *(const float4*)(wrow + kb);
        v[0] = a.x; v[1] = a.y; v[2] = a.z; v[3] = a.w;
        if (kb + 4 < Hn) {
            float4 b = *(const float4*)(wrow + kb + 4);
            v[4] = b.x; v[5] = b.y; v[6] = b.z; v[7] = b.w;
        }
    }
    return pack_bf8(v);
}

// A-frag read, XOR-swizzled frag-major layout: cell(m,s) = s*16 + (m^s).
// Lane (l,q) needs A[m=l][k=kt*32+q*8+j] -> cell q*16 + (l^q).
__device__ __forceinline__ short8 ld_af(const unsigned short* buf, int rg, int kt, int l, int q) {
    return *(const short8*)(buf + ((rg * 4 + kt) * 64 + q * 16 + (l ^ q)) * 8);
}

__global__ __launch_bounds__(512, 2) void lstm_fused(
    const float* __restrict__ x,     // (T,B)
    const float* __restrict__ W1,    // (100,1)
    const float* __restrict__ b1,    // (100,)
    const float* __restrict__ Wih1,  // (400,100)
    const float* __restrict__ bih1,  // (400,)
    const float* __restrict__ bhh1,  // (400,)
    const float* __restrict__ Whh1,  // (400,100)
    const float* __restrict__ Wih2,  // (400,100)
    const float* __restrict__ Whh2,  // (400,100)
    const float* __restrict__ bih2,  // (400,)
    const float* __restrict__ bhh2,  // (400,)
    const float* __restrict__ W2,    // (7,700)
    const float* __restrict__ b2,    // (7,)
    float* __restrict__ out)         // (B,7)
{
    __shared__ unsigned short sm[2 * HBF_USH];  // 32 KB: h double buffer, frag-major swizzled
    unsigned short* hb0 = sm;
    unsigned short* hb1 = sm + HBF_USH;

    const int tid = threadIdx.x;
    const int ag = tid >> 6, lane = tid & 63;   // wave id == unit-block id
    const int l = lane & 15, q = lane >> 4;
    const int jcol = ag * 16 + l;               // unit column (0..127; <100 real)
    const int rowbase = blockIdx.x * 64;

    // h-write constants for this lane's unit jcol (k-dim position jcol):
    // s_w = (jcol>>3)&3; ush addr = rg*2048 + hwconst + ((4q+r)^s_w)*8
    const int s_w = ((ag & 1) << 1) | (l >> 3);
    const int hwconst = (((ag >> 1) * 64 + s_w * 16) << 3) + (l & 7);

    // zero both h buffers (covers K-pad; pad units stay exactly 0 through the recurrence)
    for (int i = tid; i < HBF_USH; i += 512) ((unsigned*)sm)[i] = 0;

    // ---- in-kernel prep (was a separate kernel): Whh1 B-frags + u1/wc1 fold ----
    short8 bf[4][4];   // [G][kt], 64 VGPR, held across phase
    load_gate_bfrags(Whh1, jcol, q, bf);

    // u1[j] = Wih1[j,:]·W1 (rank-1 FC1 fold); wc1[j] = Wih1[j,:]·b1 + bih1[j] + bhh1[j]
    float u1v[4], wc1v[4];
#pragma unroll
    for (int G = 0; G < 4; ++G) {
        float u = 0.f, w = 0.f;
        if (jcol < Hn) {
            const float* wr = Wih1 + (G * Hn + jcol) * Hn;
            for (int m = 0; m < Hn; m += 4) {
                float4 a = *(const float4*)(wr + m);
                float4 s1 = *(const float4*)(W1 + m);
                float4 s2 = *(const float4*)(b1 + m);
                u += a.x * s1.x; u += a.y * s1.y; u += a.z * s1.z; u += a.w * s1.w;
                w += a.x * s2.x; w += a.y * s2.y; w += a.z * s2.z; w += a.w * s2.w;
            }
            w += bih1[G * Hn + jcol] + bhh1[G * Hn + jcol];
        }
        u1v[G] = u;
        wc1v[G] = w;
    }

    floatx4 cst[4];   // cell state per rg, rows 4q+r, unit jcol
#pragma unroll
    for (int rg = 0; rg < 4; ++rg) cst[rg] = (floatx4){0.f, 0.f, 0.f, 0.f};

    __syncthreads();   // h buffers zeroed

    // ---- Phase 1: LSTM1, 30 steps, 1 barrier/step ----
    for (int t = 0; t < Tn; ++t) {
        const unsigned short* hc = (t & 1) ? hb1 : hb0;
        unsigned short* hn = (t & 1) ? hb0 : hb1;
#pragma unroll
        for (int rg = 0; rg < 4; ++rg) {
            float4 xv = *(const float4*)(x + t * Bn + rowbase + rg * 16 + 4 * q);
            floatx4 acc[4];
#pragma unroll
            for (int G = 0; G < 4; ++G)
#pragma unroll
                for (int r = 0; r < 4; ++r)
                    acc[G][r] = fmaf(xv[r], u1v[G], wc1v[G]);
#pragma unroll
            for (int kt = 0; kt < 4; ++kt) {
                short8 a = ld_af(hc, rg, kt, l, q);
#pragma unroll
                for (int G = 0; G < 4; ++G)
                    acc[G] = __builtin_amdgcn_mfma_f32_16x16x32_bf16(a, bf[G][kt], acc[G], 0, 0, 0);
            }
#pragma unroll
            for (int r = 0; r < 4; ++r) {
                float iv = sig_(acc[0][r]);
                float fv = sig_(acc[1][r]);
                float gv = tanh_(acc[2][r]);
                float ov = sig_(acc[3][r]);
                float cc = fv * cst[rg][r] + iv * gv;
                cst[rg][r] = cc;
                hn[rg * 2048 + hwconst + (((4 * q + r) ^ s_w) << 3)] =
                    (unsigned short)f2bf(ov * tanh_(cc));
            }
        }
        __syncthreads();
    }
    // hb0 holds `last` (h after t=29).

    // ---- Wih2 frags (in-kernel convert); gin2 = bias2 + last·Wih2^T in packed VGPRs ----
    load_gate_bfrags(Wih2, jcol, q, bf);
    uint2 g2r[4][4];   // [rg][G] packed bf16 gin2 (wave-private cells)
    {
        float bv[4];
#pragma unroll
        for (int G = 0; G < 4; ++G)
            bv[G] = (jcol < Hn) ? (bih2[G * Hn + jcol] + bhh2[G * Hn + jcol]) : 0.f;
#pragma unroll
        for (int rg = 0; rg < 4; ++rg) {
            floatx4 acc[4];
#pragma unroll
            for (int G = 0; G < 4; ++G)
                acc[G] = (floatx4){bv[G], bv[G], bv[G], bv[G]};
#pragma unroll
            for (int kt = 0; kt < 4; ++kt) {
                short8 a = ld_af(hb0, rg, kt, l, q);
#pragma unroll
                for (int G = 0; G < 4; ++G)
                    acc[G] = __builtin_amdgcn_mfma_f32_16x16x32_bf16(a, bf[G][kt], acc[G], 0, 0, 0);
            }
#pragma unroll
            for (int G = 0; G < 4; ++G) {
                g2r[rg][G].x = f2bf(acc[G][0]) | (f2bf(acc[G][1]) << 16);
                g2r[rg][G].y = f2bf(acc[G][2]) | (f2bf(acc[G][3]) << 16);
            }
        }
    }
    // ---- Whh2 frags (in-kernel convert) ----
    load_gate_bfrags(Whh2, jcol, q, bf);

    // ---- Phase 2: LSTM2, 7 steps; FC2 via MFMA on waves ag<4 (rg = ag) ----
    floatx4 yfc = (floatx4){0.f, 0.f, 0.f, 0.f};

    for (int ps = 0; ps < Pn; ++ps) {
        int t = Tn + ps;
        const unsigned short* hc = (t & 1) ? hb1 : hb0;
        unsigned short* hn = (t & 1) ? hb0 : hb1;
#pragma unroll
        for (int rg = 0; rg < 4; ++rg) {
            floatx4 acc[4];
#pragma unroll
            for (int G = 0; G < 4; ++G) {
                acc[G][0] = __uint_as_float(g2r[rg][G].x << 16);
                acc[G][1] = __uint_as_float(g2r[rg][G].x & 0xFFFF0000u);
                acc[G][2] = __uint_as_float(g2r[rg][G].y << 16);
                acc[G][3] = __uint_as_float(g2r[rg][G].y & 0xFFFF0000u);
            }
#pragma unroll
            for (int kt = 0; kt < 4; ++kt) {
                short8 a = ld_af(hc, rg, kt, l, q);
#pragma unroll
                for (int G = 0; G < 4; ++G)
                    acc[G] = __builtin_amdgcn_mfma_f32_16x16x32_bf16(a, bf[G][kt], acc[G], 0, 0, 0);
            }
#pragma unroll
            for (int r = 0; r < 4; ++r) {
                float iv = sig_(acc[0][r]);
                float fv = sig_(acc[1][r]);
                float gv = tanh_(acc[2][r]);
                float ov = sig_(acc[3][r]);
                float cc = fv * cst[rg][r] + iv * gv;
                cst[rg][r] = cc;
                hn[rg * 2048 + hwconst + (((4 * q + r) ^ s_w) << 3)] =
                    (unsigned short)f2bf(ov * tanh_(cc));
            }
        }
        // FC2: y[row][p] += h2^(ps) · W2-slice(ps-1); hc = h2 of previous step (stable)
        if (ag < 4 && ps >= 1) {
#pragma unroll
            for (int kt = 0; kt < 4; ++kt) {
                short8 a = ld_af(hc, ag, kt, l, q);
                short8 wf = load_w2_frag(W2, ps - 1, kt, l, q);
                yfc = __builtin_amdgcn_mfma_f32_16x16x32_bf16(a, wf, yfc, 0, 0, 0);
            }
        }
        __syncthreads();
    }

    // ---- final FC2 (h2^(7) in hb1: t=36 even -> hn=hb1, slice 6), bias+sigmoid+store ----
    if (ag < 4) {
#pragma unroll
        for (int kt = 0; kt < 4; ++kt) {
            short8 a = ld_af(hb1, ag, kt, l, q);
            short8 wf = load_w2_frag(W2, 6, kt, l, q);
            yfc = __builtin_amdgcn_mfma_f32_16x16x32_bf16(a, wf, yfc, 0, 0, 0);
        }
        if (l < Pn) {
            float bias = b2[l];
#pragma unroll
            for (int r = 0; r < 4; ++r)
                out[(rowbase + ag * 16 + 4 * q + r) * Pn + l] = sig_(yfc[r] + bias);
        }
    }
}

extern "C" void kernel_launch(void* const* d_in, const int* in_sizes, int n_in,
                              void* d_out, int out_size, void* d_ws, size_t ws_size,
                              hipStream_t stream) {
    const float* x    = (const float*)d_in[0];
    const float* W1   = (const float*)d_in[1];
    const float* b1   = (const float*)d_in[2];
    const float* Wih1 = (const float*)d_in[3];
    const float* Whh1 = (const float*)d_in[4];
    const float* bih1 = (const float*)d_in[5];
    const float* bhh1 = (const float*)d_in[6];
    const float* Wih2 = (const float*)d_in[7];
    const float* Whh2 = (const float*)d_in[8];
    const float* bih2 = (const float*)d_in[9];
    const float* bhh2 = (const float*)d_in[10];
    const float* W2   = (const float*)d_in[11];
    const float* b2   = (const float*)d_in[12];
    float* out = (float*)d_out;

    lstm_fused<<<Bn / 64, 512, 0, stream>>>(x, W1, b1, Wih1, bih1, bhh1, Whh1,
                                            Wih2, Whh2, bih2, bhh2, W2, b2, out);
}